// Round 9
// baseline (2553.079 us; speedup 1.0000x reference)
//
#include <hip/hip_runtime.h>

#define DD 512
#define MM 4
#define BB 4
#define SS 128
#define KK 32
#define NSTEPS 16
#define EPSF 1e-6f
#define SCALEF 0.04419417382415922f  // 512^-0.5

typedef unsigned short u16;
typedef __bf16 bf16x8 __attribute__((ext_vector_type(8)));
typedef u16 u16x8 __attribute__((ext_vector_type(8)));
typedef float f32x16 __attribute__((ext_vector_type(16)));

__device__ inline void split_bf16(float x, u16& h, u16& l) {
  __bf16 hb = (__bf16)x;
  float hf = (float)hb;
  __bf16 lb = (__bf16)(x - hf);
  h = __builtin_bit_cast(u16, hb);
  l = __builtin_bit_cast(u16, lb);
}

// ---------------- weight fp32 -> split bf16 [row][1024] (hi | lo) ----------------
__global__ void k_convw(const float* __restrict__ src, u16* __restrict__ dst) {
  int idx = blockIdx.x * 256 + threadIdx.x;
  int row = idx >> 9, k = idx & 511;
  u16 h, l;
  split_bf16(src[idx], h, l);
  dst[(size_t)row * 1024 + k] = h;
  dst[(size_t)row * 1024 + 512 + k] = l;
}

// ---------------- init ----------------
__global__ void k_init(const float* __restrict__ xr, const float* __restrict__ xi,
                       float* __restrict__ sr, float* __restrict__ si,
                       float* __restrict__ acc, float* __restrict__ memv,
                       float* __restrict__ ptrv, float* __restrict__ rem,
                       u16* __restrict__ crbf, u16* __restrict__ cibf) {
  int idx = blockIdx.x * 256 + threadIdx.x;
  if (idx < BB * SS * 2 * DD) acc[idx] = 0.f;
  if (idx < BB * SS * DD) {
    float a = xr[idx], b = xi[idx];
    sr[idx] = a; si[idx] = b;
    int row = idx >> 9, d = idx & 511;
    u16 h, l;
    split_bf16(a, h, l);
    crbf[(size_t)row * 1024 + d] = h;
    crbf[(size_t)row * 1024 + 512 + d] = l;
    split_bf16(b, h, l);
    cibf[(size_t)row * 1024 + d] = h;
    cibf[(size_t)row * 1024 + 512 + d] = l;
  }
  if (idx < BB * KK * 2 * DD) memv[idx] = 0.f;
  if (idx < BB * KK) ptrv[idx] = ((idx & (KK - 1)) == 0) ? 1.f : 0.f;
  if (idx < BB) rem[idx] = 1.f;
}

// ---------------- flat_in + control softmax + ptr update + zero logit accs ----------------
__global__ void k_flatctrl(const float* __restrict__ sr, const float* __restrict__ si,
                           const float* __restrict__ ctrl_w, const float* __restrict__ ctrl_b,
                           float* __restrict__ ptrv, float* __restrict__ flat_in,
                           float* __restrict__ nptrg, float* __restrict__ wmg,
                           float* __restrict__ stacc,
                           float* __restrict__ scorev, float* __restrict__ confv,
                           float* __restrict__ haltacc) {
  int b = blockIdx.x;
  int tid = threadIdx.x;  // 256
  __shared__ float red[3 * 256];
  __shared__ float ctrl[3], optr[KK], nptr_s[KK], wm_s[KK], normf;

  int zid = b * 256 + tid;
  scorev[zid] = 0.f; scorev[zid + 1024] = 0.f;
  confv[zid] = 0.f; confv[zid + 1024] = 0.f;
  haltacc[zid] = 0.f; haltacc[zid + 1024] = 0.f;

  if (tid < KK) optr[tid] = ptrv[b * KK + tid];

  int e4 = tid * 4;
  const float* basep = (e4 < DD) ? sr : si;
  int d4 = (e4 < DD) ? e4 : (e4 - DD);
  float4 accv = make_float4(0.f, 0.f, 0.f, 0.f);
  size_t base = (size_t)b * SS * DD + d4;
  for (int s = 0; s < SS; s++) {
    float4 v = *(const float4*)&basep[base + (size_t)s * DD];
    accv.x += v.x; accv.y += v.y; accv.z += v.z; accv.w += v.w;
  }
  accv.x *= (1.0f / SS); accv.y *= (1.0f / SS); accv.z *= (1.0f / SS); accv.w *= (1.0f / SS);
  *(float4*)&flat_in[b * 2 * DD + e4] = accv;
  float fv[4] = {accv.x, accv.y, accv.z, accv.w};
  float d0 = 0.f, d1 = 0.f, d2 = 0.f;
#pragma unroll
  for (int j = 0; j < 4; j++) {
    d0 += fv[j] * ctrl_w[(e4 + j) * 3 + 0];
    d1 += fv[j] * ctrl_w[(e4 + j) * 3 + 1];
    d2 += fv[j] * ctrl_w[(e4 + j) * 3 + 2];
  }
  red[tid] = d0; red[256 + tid] = d1; red[512 + tid] = d2;
  __syncthreads();
  for (int off = 128; off > 0; off >>= 1) {
    if (tid < off) {
      red[tid] += red[tid + off];
      red[256 + tid] += red[256 + tid + off];
      red[512 + tid] += red[512 + tid + off];
    }
    __syncthreads();
  }
  if (tid == 0) {
    float l0 = red[0] + ctrl_b[0], l1 = red[256] + ctrl_b[1], l2 = red[512] + ctrl_b[2];
    float mx = fmaxf(l0, fmaxf(l1, l2));
    float e0 = expf(l0 - mx), e1 = expf(l1 - mx), e2 = expf(l2 - mx);
    float s = e0 + e1 + e2;
    ctrl[0] = e0 / s; ctrl[1] = e1 / s; ctrl[2] = e2 / s;
    stacc[b * 2] = 0.f; stacc[b * 2 + 1] = 0.f;
  }
  __syncthreads();
  if (tid < KK) {
    float up = optr[(tid + KK - 1) & (KK - 1)];
    float dn = optr[(tid + 1) & (KK - 1)];
    float cu = optr[tid];
    nptr_s[tid] = ctrl[0] * up + ctrl[1] * dn + ctrl[2] * cu;
    wm_s[tid] = ctrl[0] * up;
  }
  __syncthreads();
  if (tid == 0) {
    float s = 0.f;
    for (int k = 0; k < KK; k++) s += nptr_s[k];
    normf = 1.f / (s + EPSF);
  }
  __syncthreads();
  if (tid < KK) {
    float np = nptr_s[tid] * normf;
    ptrv[b * KK + tid] = np;
    nptrg[b * KK + tid] = np;
    wmg[b * KK + tid] = wm_s[tid];
  }
}

#define LSTR 72  // LDS row stride in bf16 elems

// ---------------- Wl complex NT GEMM, software-pipelined (fp32 out) ----------------
__global__ __launch_bounds__(256) void k_gemm_mfma(
    const u16* __restrict__ Ar, const u16* __restrict__ Ai,
    const u16* __restrict__ Wr, const u16* __restrict__ Wi,
    float* __restrict__ Cr, float* __restrict__ Ci) {
  __shared__ u16 sAr[64][LSTR], sAi[64][LSTR], sWr[64][LSTR], sWi[64][LSTR];
  int m = blockIdx.z;
  int row_blk = blockIdx.y * 64, o_blk = blockIdx.x * 64;
  int tid = threadIdx.x;

  int lrow = tid >> 3, lk8 = (tid & 7) << 3;
  size_t arow0 = (size_t)(row_blk + lrow), arow1 = arow0 + 32;
  size_t wrow0 = (size_t)m * DD + o_blk + lrow, wrow1 = wrow0 + 32;

  int wave = tid >> 6, lane = tid & 63;
  int wrow = (wave >> 1) * 32, wcol = (wave & 1) * 32;
  int l31 = lane & 31, khalf = (lane >> 5) * 8;

  f32x16 accP, accN, accI;
  for (int i = 0; i < 16; i++) { accP[i] = 0.f; accN[i] = 0.f; accI[i] = 0.f; }

  u16x8 g0 = *(const u16x8*)&Ar[arow0 * 1024 + lk8];
  u16x8 g1 = *(const u16x8*)&Ar[arow1 * 1024 + lk8];
  u16x8 g2 = *(const u16x8*)&Ai[arow0 * 1024 + lk8];
  u16x8 g3 = *(const u16x8*)&Ai[arow1 * 1024 + lk8];
  u16x8 g4 = *(const u16x8*)&Wr[wrow0 * 1024 + lk8];
  u16x8 g5 = *(const u16x8*)&Wr[wrow1 * 1024 + lk8];
  u16x8 g6 = *(const u16x8*)&Wi[wrow0 * 1024 + lk8];
  u16x8 g7 = *(const u16x8*)&Wi[wrow1 * 1024 + lk8];

  for (int it = 0; it < 24; ++it) {
    __syncthreads();
    *(u16x8*)&sAr[lrow][lk8] = g0;
    *(u16x8*)&sAr[lrow + 32][lk8] = g1;
    *(u16x8*)&sAi[lrow][lk8] = g2;
    *(u16x8*)&sAi[lrow + 32][lk8] = g3;
    *(u16x8*)&sWr[lrow][lk8] = g4;
    *(u16x8*)&sWr[lrow + 32][lk8] = g5;
    *(u16x8*)&sWi[lrow][lk8] = g6;
    *(u16x8*)&sWi[lrow + 32][lk8] = g7;
    u16x8 n0, n1, n2, n3, n4, n5, n6, n7;
    if (it < 23) {
      int it2 = it + 1, seg = it2 >> 3, k0 = (it2 & 7) * 64;
      int aofs = (seg == 1) ? 512 : 0, wofs = (seg == 2) ? 512 : 0;
      n0 = *(const u16x8*)&Ar[arow0 * 1024 + aofs + k0 + lk8];
      n1 = *(const u16x8*)&Ar[arow1 * 1024 + aofs + k0 + lk8];
      n2 = *(const u16x8*)&Ai[arow0 * 1024 + aofs + k0 + lk8];
      n3 = *(const u16x8*)&Ai[arow1 * 1024 + aofs + k0 + lk8];
      n4 = *(const u16x8*)&Wr[wrow0 * 1024 + wofs + k0 + lk8];
      n5 = *(const u16x8*)&Wr[wrow1 * 1024 + wofs + k0 + lk8];
      n6 = *(const u16x8*)&Wi[wrow0 * 1024 + wofs + k0 + lk8];
      n7 = *(const u16x8*)&Wi[wrow1 * 1024 + wofs + k0 + lk8];
    }
    __syncthreads();
#pragma unroll
    for (int kk = 0; kk < 64; kk += 16) {
      bf16x8 fAr = *(const bf16x8*)&sAr[wrow + l31][kk + khalf];
      bf16x8 fAi = *(const bf16x8*)&sAi[wrow + l31][kk + khalf];
      bf16x8 fWr = *(const bf16x8*)&sWr[wcol + l31][kk + khalf];
      bf16x8 fWi = *(const bf16x8*)&sWi[wcol + l31][kk + khalf];
      accP = __builtin_amdgcn_mfma_f32_32x32x16_bf16(fAr, fWr, accP, 0, 0, 0);
      accN = __builtin_amdgcn_mfma_f32_32x32x16_bf16(fAi, fWi, accN, 0, 0, 0);
      accI = __builtin_amdgcn_mfma_f32_32x32x16_bf16(fAi, fWr, accI, 0, 0, 0);
      accI = __builtin_amdgcn_mfma_f32_32x32x16_bf16(fAr, fWi, accI, 0, 0, 0);
    }
    if (it < 23) {
      g0 = n0; g1 = n1; g2 = n2; g3 = n3; g4 = n4; g5 = n5; g6 = n6; g7 = n7;
    }
  }

  int o = o_blk + wcol + l31;
#pragma unroll
  for (int reg = 0; reg < 16; reg++) {
    int r_in = (reg & 3) + 8 * (reg >> 2) + 4 * (lane >> 5);
    int gr = row_blk + wrow + r_in;
    int b = gr >> 7, s = gr & (SS - 1);
    size_t crow = (size_t)((b * MM + m) * SS + s);
    Cr[crow * DD + o] = accP[reg] - accN[reg];
    Ci[crow * DD + o] = accI[reg];
  }
}

// ---------------- merged Q/K/V GEMM, 128x64 tile, 512 threads, pipelined ----------------
__global__ __launch_bounds__(512) void k_gemm_qkv(
    const u16* __restrict__ Ar, const u16* __restrict__ Ai,
    const u16* __restrict__ wbf, size_t WSLOT,
    u16* __restrict__ qbr, u16* __restrict__ qbi,
    u16* __restrict__ kbr, u16* __restrict__ kbi,
    u16* __restrict__ vbr, u16* __restrict__ vbi) {
  __shared__ u16 sAr[128][LSTR], sAi[128][LSTR], sWr[64][LSTR], sWi[64][LSTR];
  int zid = blockIdx.z;
  int m = zid / 3, w = zid - 3 * m;
  const u16* Wr = wbf + (size_t)(2 + 2 * w) * WSLOT;
  const u16* Wi = Wr + WSLOT;
  int b = blockIdx.y;                 // 128-row tile == one batch
  int o_blk = blockIdx.x * 64;
  int tid = threadIdx.x;

  int lrow = tid >> 3, lk8 = (tid & 7) << 3;   // lrow 0..63
  size_t abase = (size_t)((b * MM + m) * SS);
  size_t arow0 = abase + lrow, arow1 = abase + lrow + 64;
  size_t wrow0 = (size_t)m * DD + o_blk + lrow;

  int wave = tid >> 6, lane = tid & 63;        // 8 waves
  int wrow = (wave >> 1) * 32;                 // 0,32,64,96
  int wcol = (wave & 1) * 32;                  // 0,32
  int l31 = lane & 31, khalf = (lane >> 5) * 8;

  f32x16 accP, accN, accI;
  for (int i = 0; i < 16; i++) { accP[i] = 0.f; accN[i] = 0.f; accI[i] = 0.f; }

  u16x8 g0 = *(const u16x8*)&Ar[arow0 * 1024 + lk8];
  u16x8 g1 = *(const u16x8*)&Ar[arow1 * 1024 + lk8];
  u16x8 g2 = *(const u16x8*)&Ai[arow0 * 1024 + lk8];
  u16x8 g3 = *(const u16x8*)&Ai[arow1 * 1024 + lk8];
  u16x8 g4 = *(const u16x8*)&Wr[wrow0 * 1024 + lk8];
  u16x8 g5 = *(const u16x8*)&Wi[wrow0 * 1024 + lk8];

  for (int it = 0; it < 24; ++it) {
    __syncthreads();
    *(u16x8*)&sAr[lrow][lk8] = g0;
    *(u16x8*)&sAr[lrow + 64][lk8] = g1;
    *(u16x8*)&sAi[lrow][lk8] = g2;
    *(u16x8*)&sAi[lrow + 64][lk8] = g3;
    *(u16x8*)&sWr[lrow][lk8] = g4;
    *(u16x8*)&sWi[lrow][lk8] = g5;
    u16x8 n0, n1, n2, n3, n4, n5;
    if (it < 23) {
      int it2 = it + 1, seg = it2 >> 3, k0 = (it2 & 7) * 64;
      int aofs = (seg == 1) ? 512 : 0, wofs = (seg == 2) ? 512 : 0;
      n0 = *(const u16x8*)&Ar[arow0 * 1024 + aofs + k0 + lk8];
      n1 = *(const u16x8*)&Ar[arow1 * 1024 + aofs + k0 + lk8];
      n2 = *(const u16x8*)&Ai[arow0 * 1024 + aofs + k0 + lk8];
      n3 = *(const u16x8*)&Ai[arow1 * 1024 + aofs + k0 + lk8];
      n4 = *(const u16x8*)&Wr[wrow0 * 1024 + wofs + k0 + lk8];
      n5 = *(const u16x8*)&Wi[wrow0 * 1024 + wofs + k0 + lk8];
    }
    __syncthreads();
#pragma unroll
    for (int kk = 0; kk < 64; kk += 16) {
      bf16x8 fAr = *(const bf16x8*)&sAr[wrow + l31][kk + khalf];
      bf16x8 fAi = *(const bf16x8*)&sAi[wrow + l31][kk + khalf];
      bf16x8 fWr = *(const bf16x8*)&sWr[wcol + l31][kk + khalf];
      bf16x8 fWi = *(const bf16x8*)&sWi[wcol + l31][kk + khalf];
      accP = __builtin_amdgcn_mfma_f32_32x32x16_bf16(fAr, fWr, accP, 0, 0, 0);
      accN = __builtin_amdgcn_mfma_f32_32x32x16_bf16(fAi, fWi, accN, 0, 0, 0);
      accI = __builtin_amdgcn_mfma_f32_32x32x16_bf16(fAi, fWr, accI, 0, 0, 0);
      accI = __builtin_amdgcn_mfma_f32_32x32x16_bf16(fAr, fWi, accI, 0, 0, 0);
    }
    if (it < 23) {
      g0 = n0; g1 = n1; g2 = n2; g3 = n3; g4 = n4; g5 = n5;
    }
  }

  u16* Cr = (w == 0) ? qbr : ((w == 1) ? kbr : vbr);
  u16* Ci = (w == 0) ? qbi : ((w == 1) ? kbi : vbi);
  int o = o_blk + wcol + l31;
#pragma unroll
  for (int reg = 0; reg < 16; reg++) {
    int r_in = (reg & 3) + 8 * (reg >> 2) + 4 * (lane >> 5);
    int s = wrow + r_in;                 // 0..127
    size_t crow = abase + s;
    u16 h, l;
    split_bf16(accP[reg] - accN[reg], h, l);
    Cr[crow * 1024 + o] = h;
    Cr[crow * 1024 + 512 + o] = l;
    split_bf16(accI[reg], h, l);
    Ci[crow * 1024 + o] = h;
    Ci[crow * 1024 + 512 + o] = l;
  }
}

// ---------------- scores (32 rows x 128 cols per block) + fused softmax -> split P ----------------
__global__ __launch_bounds__(256) void k_scores_sm(
    const u16* __restrict__ Q_r, const u16* __restrict__ Q_i,
    const u16* __restrict__ K_r, const u16* __restrict__ K_i,
    u16* __restrict__ Pb) {
  __shared__ __align__(16) char smem[46080];
  u16 (*sQr)[LSTR] = (u16(*)[LSTR])smem;
  u16 (*sQi)[LSTR] = (u16(*)[LSTR])(smem + 4608);
  u16 (*sKr)[LSTR] = (u16(*)[LSTR])(smem + 9216);
  u16 (*sKi)[LSTR] = (u16(*)[LSTR])(smem + 27648);
  float (*stile)[132] = (float(*)[132])smem;

  int bm = blockIdx.z;
  int s_blk = blockIdx.y * 32;
  int tid = threadIdx.x;
  int lrow = tid >> 3, lk8 = (tid & 7) << 3;
  size_t qrow = (size_t)(bm * SS + s_blk + lrow);
  size_t krow = (size_t)(bm * SS + lrow);

  int wave = tid >> 6, lane = tid & 63;
  int tcol_w = wave * 32;
  int l31 = lane & 31, khalf = (lane >> 5) * 8;

  f32x16 acc;
  for (int i = 0; i < 16; i++) acc[i] = 0.f;

  for (int it = 0; it < 24; ++it) {
    int seg = it >> 3, k0 = (it & 7) * 64;
    int qofs = (seg == 1) ? 512 : 0;
    int kofs = (seg == 2) ? 512 : 0;
    u16x8 q0 = *(const u16x8*)&Q_r[qrow * 1024 + qofs + k0 + lk8];
    u16x8 q1 = *(const u16x8*)&Q_i[qrow * 1024 + qofs + k0 + lk8];
    u16x8 kr0 = *(const u16x8*)&K_r[(krow + 0) * 1024 + kofs + k0 + lk8];
    u16x8 kr1 = *(const u16x8*)&K_r[(krow + 32) * 1024 + kofs + k0 + lk8];
    u16x8 kr2 = *(const u16x8*)&K_r[(krow + 64) * 1024 + kofs + k0 + lk8];
    u16x8 kr3 = *(const u16x8*)&K_r[(krow + 96) * 1024 + kofs + k0 + lk8];
    u16x8 ki0 = *(const u16x8*)&K_i[(krow + 0) * 1024 + kofs + k0 + lk8];
    u16x8 ki1 = *(const u16x8*)&K_i[(krow + 32) * 1024 + kofs + k0 + lk8];
    u16x8 ki2 = *(const u16x8*)&K_i[(krow + 64) * 1024 + kofs + k0 + lk8];
    u16x8 ki3 = *(const u16x8*)&K_i[(krow + 96) * 1024 + kofs + k0 + lk8];
    __syncthreads();
    *(u16x8*)&sQr[lrow][lk8] = q0;
    *(u16x8*)&sQi[lrow][lk8] = q1;
    *(u16x8*)&sKr[lrow][lk8] = kr0;
    *(u16x8*)&sKr[lrow + 32][lk8] = kr1;
    *(u16x8*)&sKr[lrow + 64][lk8] = kr2;
    *(u16x8*)&sKr[lrow + 96][lk8] = kr3;
    *(u16x8*)&sKi[lrow][lk8] = ki0;
    *(u16x8*)&sKi[lrow + 32][lk8] = ki1;
    *(u16x8*)&sKi[lrow + 64][lk8] = ki2;
    *(u16x8*)&sKi[lrow + 96][lk8] = ki3;
    __syncthreads();
#pragma unroll
    for (int kk = 0; kk < 64; kk += 16) {
      bf16x8 fQr = *(const bf16x8*)&sQr[l31][kk + khalf];
      bf16x8 fQi = *(const bf16x8*)&sQi[l31][kk + khalf];
      bf16x8 fKr = *(const bf16x8*)&sKr[tcol_w + l31][kk + khalf];
      bf16x8 fKi = *(const bf16x8*)&sKi[tcol_w + l31][kk + khalf];
      acc = __builtin_amdgcn_mfma_f32_32x32x16_bf16(fQr, fKr, acc, 0, 0, 0);
      acc = __builtin_amdgcn_mfma_f32_32x32x16_bf16(fQi, fKi, acc, 0, 0, 0);
    }
  }

  __syncthreads();
#pragma unroll
  for (int reg = 0; reg < 16; reg++) {
    int r = (reg & 3) + 8 * (reg >> 2) + 4 * (lane >> 5);
    stile[r][tcol_w + l31] = acc[reg] * SCALEF;
  }
  __syncthreads();
  int row = tid >> 3;
  int oct = tid & 7;
  float mx = -3.4e38f;
#pragma unroll
  for (int j = 0; j < 16; j++) mx = fmaxf(mx, stile[row][oct * 16 + j]);
  mx = fmaxf(mx, __shfl_xor(mx, 1));
  mx = fmaxf(mx, __shfl_xor(mx, 2));
  mx = fmaxf(mx, __shfl_xor(mx, 4));
  float ev[16];
  float sum = 0.f;
#pragma unroll
  for (int j = 0; j < 16; j++) {
    ev[j] = expf(stile[row][oct * 16 + j] - mx);
    sum += ev[j];
  }
  sum += __shfl_xor(sum, 1);
  sum += __shfl_xor(sum, 2);
  sum += __shfl_xor(sum, 4);
  float inv = 1.f / sum;
  size_t prow = (size_t)(bm * SS + s_blk + row) * 256;
#pragma unroll
  for (int j = 0; j < 16; j++) {
    int c = oct * 16 + j;
    u16 h, l;
    split_bf16(ev[j] * inv, h, l);
    Pb[prow + c] = h;
    Pb[prow + 128 + c] = l;
  }
}

// ---------------- P x V MFMA + gate -> pr/pi, fused score/conf/halt logit partials ----------------
__global__ __launch_bounds__(256) void k_pv(
    const u16* __restrict__ Pb, const u16* __restrict__ vbr, const u16* __restrict__ vbi,
    const float* __restrict__ gate_mask,
    const float* __restrict__ score_w, const float* __restrict__ conf_w,
    const float* __restrict__ halt_w,
    float* __restrict__ pr, float* __restrict__ pi,
    float* __restrict__ scorev, float* __restrict__ confv, float* __restrict__ haltacc) {
  __shared__ u16 sP[64][LSTR], sVr[64][LSTR], sVi[64][LSTR];
  __shared__ float rowAcc[64][3];
  int bm = blockIdx.z;
  int m = bm & (MM - 1);
  int s_blk = blockIdx.y * 64;
  int o_blk = blockIdx.x * 64;
  int tid = threadIdx.x;
  int lrow = tid >> 3, lk8 = (tid & 7) << 3;
  size_t prow0 = (size_t)(bm * SS + s_blk + lrow), prow1 = prow0 + 32;

  int wave = tid >> 6, lane = tid & 63;
  int wrow = (wave >> 1) * 32;
  int wcol = (wave & 1) * 32;
  int l31 = lane & 31, khalf = (lane >> 5) * 8;

  if (tid < 64) { rowAcc[tid][0] = 0.f; rowAcc[tid][1] = 0.f; rowAcc[tid][2] = 0.f; }

  f32x16 accR, accI;
  for (int i = 0; i < 16; i++) { accR[i] = 0.f; accI[i] = 0.f; }

  for (int it = 0; it < 6; ++it) {
    int seg = it >> 1, k0 = (it & 1) * 64;
    int pofs = (seg == 1) ? 128 : 0;
    int vofs = (seg == 2) ? 512 : 0;
    u16x8 p0 = *(const u16x8*)&Pb[prow0 * 256 + pofs + k0 + lk8];
    u16x8 p1 = *(const u16x8*)&Pb[prow1 * 256 + pofs + k0 + lk8];
    size_t vrow0 = (size_t)(bm * SS + k0 + lrow), vrow1 = vrow0 + 32;
    u16x8 v0 = *(const u16x8*)&vbr[vrow0 * 1024 + vofs + o_blk + lk8];
    u16x8 v1 = *(const u16x8*)&vbr[vrow1 * 1024 + vofs + o_blk + lk8];
    u16x8 w0 = *(const u16x8*)&vbi[vrow0 * 1024 + vofs + o_blk + lk8];
    u16x8 w1 = *(const u16x8*)&vbi[vrow1 * 1024 + vofs + o_blk + lk8];
    __syncthreads();
    *(u16x8*)&sP[lrow][lk8] = p0;
    *(u16x8*)&sP[lrow + 32][lk8] = p1;
    *(u16x8*)&sVr[lrow][lk8] = v0;
    *(u16x8*)&sVr[lrow + 32][lk8] = v1;
    *(u16x8*)&sVi[lrow][lk8] = w0;
    *(u16x8*)&sVi[lrow + 32][lk8] = w1;
    __syncthreads();
#pragma unroll
    for (int kk = 0; kk < 64; kk += 16) {
      bf16x8 fP = *(const bf16x8*)&sP[wrow + l31][kk + khalf];
      u16x8 ar, ai;
#pragma unroll
      for (int j = 0; j < 8; j++) {
        ar[j] = sVr[kk + khalf + j][wcol + l31];
        ai[j] = sVi[kk + khalf + j][wcol + l31];
      }
      accR = __builtin_amdgcn_mfma_f32_32x32x16_bf16(fP, __builtin_bit_cast(bf16x8, ar), accR, 0, 0, 0);
      accI = __builtin_amdgcn_mfma_f32_32x32x16_bf16(fP, __builtin_bit_cast(bf16x8, ai), accI, 0, 0, 0);
    }
  }

  int d = o_blk + wcol + l31;
  float g = 1.f / (1.f + expf(-gate_mask[m * DD + d]));
  float sw_r = score_w[m * 1024 + d], sw_i = score_w[m * 1024 + 512 + d];
  float cw_r = conf_w[m * 1024 + d],  cw_i = conf_w[m * 1024 + 512 + d];
  float hw_r = halt_w[m * 1024 + d],  hw_i = halt_w[m * 1024 + 512 + d];
#pragma unroll
  for (int reg = 0; reg < 16; reg++) {
    int r_in = (reg & 3) + 8 * (reg >> 2) + 4 * (lane >> 5);
    size_t crow = (size_t)(bm * SS + s_blk + wrow + r_in);
    float pR = accR[reg] * g, pI = accI[reg] * g;
    pr[crow * DD + d] = pR;
    pi[crow * DD + d] = pI;
    float sp = pR * sw_r + pI * sw_i;
    float cp = pR * cw_r + pI * cw_i;
    float hp = pR * hw_r + pI * hw_i;
#pragma unroll
    for (int msk = 16; msk >= 1; msk >>= 1) {
      sp += __shfl_xor(sp, msk);
      cp += __shfl_xor(cp, msk);
      hp += __shfl_xor(hp, msk);
    }
    if (l31 == 0) {
      int r = wrow + r_in;
      atomicAdd(&rowAcc[r][0], sp);
      atomicAdd(&rowAcc[r][1], cp);
      atomicAdd(&rowAcc[r][2], hp);
    }
  }
  __syncthreads();
  if (tid < 64) {
    size_t rowg = (size_t)(bm * SS + s_blk + tid);
    atomicAdd(&scorev[rowg], rowAcc[tid][0]);
    atomicAdd(&confv[rowg], rowAcc[tid][1]);
    atomicAdd(&haltacc[rowg], rowAcc[tid][2]);
  }
}

// ---------------- magnitude LN + phase renorm + mod scale -> split bf16 ----------------
__global__ void k_lnphase(const float* __restrict__ zr, const float* __restrict__ zi,
                          const float* __restrict__ ln_scale, const float* __restrict__ ln_shift,
                          const float* __restrict__ mod_bias,
                          u16* __restrict__ zbr, u16* __restrict__ zbi) {
  int row = blockIdx.x;
  int m = (row >> 7) & (MM - 1);
  int tid = threadIdx.x;  // 128
  size_t base = (size_t)row * DD;
  float zrv[4], ziv[4], rv[4];
  float sum = 0.f, sumsq = 0.f;
#pragma unroll
  for (int i = 0; i < 4; i++) {
    int o = tid + i * 128;
    float a = zr[base + o], bv = zi[base + o];
    zrv[i] = a; ziv[i] = bv;
    float r = sqrtf(a * a + bv * bv);
    rv[i] = r;
    float mg = r + EPSF;
    sum += mg;
    sumsq += mg * mg;
  }
  __shared__ float rs[128], rq[128];
  rs[tid] = sum; rq[tid] = sumsq;
  __syncthreads();
  for (int off = 64; off > 0; off >>= 1) {
    if (tid < off) { rs[tid] += rs[tid + off]; rq[tid] += rq[tid + off]; }
    __syncthreads();
  }
  float mean = rs[0] * (1.0f / DD);
  float var = (rq[0] - (float)DD * mean * mean) * (1.0f / (DD - 1));
  float inv = 1.0f / sqrtf(var + EPSF);
#pragma unroll
  for (int i = 0; i < 4; i++) {
    int o = tid + i * 128;
    float mg = rv[i] + EPSF;
    float nm = (mg - mean) * inv * ln_scale[m * DD + o] + ln_shift[m * DD + o];
    float r = rv[i];
    float cosp, sinp;
    if (r > 0.f) { cosp = zrv[i] / r; sinp = ziv[i] / r; }
    else { cosp = 1.f; sinp = 0.f; }
    float z1r = nm * cosp, z1i = nm * sinp;
    float nrm = sqrtf(z1r * z1r + z1i * z1i) + EPSF;
    float sc = fmaxf(nrm + mod_bias[m * DD + o], 0.f) / nrm;
    u16 h, l;
    split_bf16(z1r * sc, h, l);
    zbr[(size_t)row * 1024 + o] = h;
    zbr[(size_t)row * 1024 + 512 + o] = l;
    split_bf16(z1i * sc, h, l);
    zbi[(size_t)row * 1024 + o] = h;
    zbi[(size_t)row * 1024 + 512 + o] = l;
  }
}

// ---------------- stack mem update + read + st dots; chunk0 also does halt p + coeff/rem ----------------
__global__ void k_memup(const float* __restrict__ flat_in,
                        const float* __restrict__ nptrg, const float* __restrict__ wmg,
                        float* __restrict__ memv, float* __restrict__ readv,
                        const float* __restrict__ st_score_w, const float* __restrict__ st_conf_w,
                        float* __restrict__ stacc,
                        const float* __restrict__ haltacc, const float* __restrict__ halt_b,
                        const float* __restrict__ rem_in, float* __restrict__ rem_out,
                        float* __restrict__ coeff) {
  int b = blockIdx.x >> 2;
  int chunk = blockIdx.x & 3;
  int tid = threadIdx.x;           // 256
  int e = chunk * 256 + tid;
  __shared__ float nptr[KK], wm[KK];
  __shared__ float red[256], red2[256], red3[256];
  if (tid < KK) { nptr[tid] = nptrg[b * KK + tid]; wm[tid] = wmg[b * KK + tid]; }

  float hsum = 0.f;
  if (chunk == 0) {
    float h0 = haltacc[b * 512 + tid] + halt_b[tid >> 7];
    float h1 = haltacc[b * 512 + 256 + tid] + halt_b[(256 + tid) >> 7];
    hsum = 1.f / (1.f + expf(-h0)) + 1.f / (1.f + expf(-h1));
  }
  __syncthreads();
  float fl = flat_in[b * 2 * DD + e];
  float racc = 0.f;
#pragma unroll
  for (int k = 0; k < KK; k++) {
    size_t idx = ((size_t)(b * KK + k)) * 2 * DD + e;
    float nm = wm[k] * fl + memv[idx] * (1.f - wm[k]);
    memv[idx] = nm;
    racc += nm * nptr[k];
  }
  readv[b * 2 * DD + e] = racc;
  red[tid] = racc * st_score_w[e];
  red2[tid] = racc * st_conf_w[e];
  red3[tid] = hsum;
  __syncthreads();
  for (int off = 128; off > 0; off >>= 1) {
    if (tid < off) { red[tid] += red[tid + off]; red2[tid] += red2[tid + off]; red3[tid] += red3[tid + off]; }
    __syncthreads();
  }
  if (tid == 0) {
    atomicAdd(&stacc[b * 2], red[0]);
    atomicAdd(&stacc[b * 2 + 1], red2[0]);
    if (chunk == 0) {
      float p = red3[0] * (1.0f / (MM * SS));
      float r = rem_in[b];
      coeff[b] = p * r;
      rem_out[b] = r * (1.f - p);
    }
  }
}

// ---------------- module-mix softmax + stv + new state + acc + next-step c ----------------
__global__ void k_combine(const float* __restrict__ pr, const float* __restrict__ pi,
                          const float* __restrict__ scorev, const float* __restrict__ confv,
                          const float* __restrict__ score_b, const float* __restrict__ conf_b,
                          const float* __restrict__ stacc,
                          const float* __restrict__ st_score_b, const float* __restrict__ st_conf_b,
                          const float* __restrict__ readv, const float* __restrict__ coeff,
                          const float* __restrict__ xr, const float* __restrict__ xi,
                          float* __restrict__ sr, float* __restrict__ si, float* __restrict__ acc,
                          u16* __restrict__ crbf, u16* __restrict__ cibf) {
  int bs = blockIdx.x;
  int b = bs >> 7, s = bs & (SS - 1);
  int tid = threadIdx.x;  // 256
  __shared__ float w[5];
  if (tid == 0) {
    float l[5];
    for (int m = 0; m < MM; m++) {
      int r = (b * MM + m) * SS + s;
      float sc = scorev[r] + score_b[m];
      float cf2 = 1.f / (1.f + expf(-(confv[r] + conf_b[m])));
      l[m] = sc * cf2;
    }
    float sv = stacc[b * 2] + st_score_b[0];
    float cv = 1.f / (1.f + expf(-(stacc[b * 2 + 1] + st_conf_b[0])));
    l[4] = sv * cv;
    float mx = l[0];
    for (int j = 1; j < 5; j++) mx = fmaxf(mx, l[j]);
    float sum = 0.f;
    for (int j = 0; j < 5; j++) { l[j] = expf(l[j] - mx); sum += l[j]; }
    for (int j = 0; j < 5; j++) w[j] = l[j] / sum;
  }
  __syncthreads();
  float cf = coeff[b];
#pragma unroll
  for (int i = 0; i < 2; i++) {
    int d = tid + i * 256;
    float nsr = w[4] * readv[b * 2 * DD + d];
    float nsi = w[4] * readv[b * 2 * DD + DD + d];
#pragma unroll
    for (int m = 0; m < MM; m++) {
      size_t off = ((size_t)((b * MM + m) * SS + s)) * DD + d;
      nsr += w[m] * pr[off];
      nsi += w[m] * pi[off];
    }
    size_t sidx = (size_t)bs * DD + d;
    sr[sidx] = nsr;
    si[sidx] = nsi;
    size_t aoff = (size_t)bs * 2 * DD;
    acc[aoff + d] += cf * nsr;
    acc[aoff + DD + d] += cf * nsi;
    u16 h, l;
    split_bf16(0.5f * xr[sidx] + 0.5f * nsr, h, l);
    crbf[(size_t)bs * 1024 + d] = h;
    crbf[(size_t)bs * 1024 + 512 + d] = l;
    split_bf16(0.5f * xi[sidx] + 0.5f * nsi, h, l);
    cibf[(size_t)bs * 1024 + d] = h;
    cibf[(size_t)bs * 1024 + 512 + d] = l;
  }
}

// ---------------- out = acc + rem * concat(sr, si) ----------------
__global__ void k_final(const float* __restrict__ acc, const float* __restrict__ rem,
                        const float* __restrict__ sr, const float* __restrict__ si,
                        float* __restrict__ out) {
  int idx = blockIdx.x * 256 + threadIdx.x;
  int e = idx & (2 * DD - 1);
  int bs = idx >> 10;
  int b = bs >> 7;
  float v = (e < DD) ? sr[(size_t)bs * DD + e] : si[(size_t)bs * DD + e - DD];
  out[idx] = acc[idx] + rem[b] * v;
}

extern "C" void kernel_launch(void* const* d_in, const int* in_sizes, int n_in,
                              void* d_out, int out_size, void* d_ws, size_t ws_size,
                              hipStream_t stream) {
  const float* xr = (const float*)d_in[0];
  const float* xi = (const float*)d_in[1];
  const float* Wl_r = (const float*)d_in[2];
  const float* Wl_i = (const float*)d_in[3];
  const float* Wq_r = (const float*)d_in[4];
  const float* Wq_i = (const float*)d_in[5];
  const float* Wk_r = (const float*)d_in[6];
  const float* Wk_i = (const float*)d_in[7];
  const float* Wv_r = (const float*)d_in[8];
  const float* Wv_i = (const float*)d_in[9];
  const float* ln_scale = (const float*)d_in[10];
  const float* ln_shift = (const float*)d_in[11];
  const float* mod_bias = (const float*)d_in[12];
  const float* gate_mask = (const float*)d_in[13];
  const float* score_w = (const float*)d_in[14];
  const float* score_b = (const float*)d_in[15];
  const float* conf_w = (const float*)d_in[16];
  const float* conf_b = (const float*)d_in[17];
  const float* halt_w = (const float*)d_in[18];
  const float* halt_b = (const float*)d_in[19];
  const float* ctrl_w = (const float*)d_in[20];
  const float* ctrl_b = (const float*)d_in[21];
  const float* st_score_w = (const float*)d_in[22];
  const float* st_score_b = (const float*)d_in[23];
  const float* st_conf_w = (const float*)d_in[24];
  const float* st_conf_b = (const float*)d_in[25];
  float* out = (float*)d_out;

  const int BSD = BB * SS * DD;
  const int BMSD = BB * MM * SS * DD;
  const size_t WSLOT = (size_t)MM * DD * 1024;

  char* pc = (char*)d_ws;
  float* sr = (float*)pc; pc += (size_t)BSD * 4;
  float* si = (float*)pc; pc += (size_t)BSD * 4;
  float* zr = (float*)pc; pc += (size_t)BMSD * 4;
  float* zi = (float*)pc; pc += (size_t)BMSD * 4;
  float* prb = (float*)pc; pc += (size_t)BMSD * 4;
  float* pib = (float*)pc; pc += (size_t)BMSD * 4;
  float* scorev = (float*)pc; pc += (size_t)BB * MM * SS * 4;
  float* confv = (float*)pc; pc += (size_t)BB * MM * SS * 4;
  float* haltacc = (float*)pc; pc += (size_t)BB * MM * SS * 4;
  float* flat = (float*)pc; pc += (size_t)BB * 2 * DD * 4;
  float* stacc = (float*)pc; pc += 64;
  float* nptrg = (float*)pc; pc += (size_t)BB * KK * 4;
  float* wmg = (float*)pc; pc += (size_t)BB * KK * 4;
  float* memv = (float*)pc; pc += (size_t)BB * KK * 2 * DD * 4;
  float* ptrv = (float*)pc; pc += (size_t)BB * KK * 4;
  float* readv = (float*)pc; pc += (size_t)BB * 2 * DD * 4;
  float* accb = (float*)pc; pc += (size_t)BB * SS * 2 * DD * 4;
  float* rem0 = (float*)pc; pc += (size_t)BB * 4;
  float* rem1 = (float*)pc; pc += (size_t)BB * 4;
  float* coeff = (float*)pc; pc += (size_t)BB * 4;
  u16* crbf = (u16*)pc; pc += (size_t)BB * SS * 1024 * 2;
  u16* cibf = (u16*)pc; pc += (size_t)BB * SS * 1024 * 2;
  u16* zbr = (u16*)pc; pc += (size_t)BB * MM * SS * 1024 * 2;
  u16* zbi = (u16*)pc; pc += (size_t)BB * MM * SS * 1024 * 2;
  u16* qbr = (u16*)pc; pc += (size_t)BB * MM * SS * 1024 * 2;
  u16* qbi = (u16*)pc; pc += (size_t)BB * MM * SS * 1024 * 2;
  u16* kbr = (u16*)pc; pc += (size_t)BB * MM * SS * 1024 * 2;
  u16* kbi = (u16*)pc; pc += (size_t)BB * MM * SS * 1024 * 2;
  u16* vbr = (u16*)pc; pc += (size_t)BB * MM * SS * 1024 * 2;
  u16* vbi = (u16*)pc; pc += (size_t)BB * MM * SS * 1024 * 2;
  u16* Pb  = (u16*)pc; pc += (size_t)BB * MM * SS * 256 * 2;
  u16* wbf = (u16*)pc; pc += 8 * WSLOT * 2;

  k_convw<<<4096, 256, 0, stream>>>(Wl_r, wbf + 0 * WSLOT);
  k_convw<<<4096, 256, 0, stream>>>(Wl_i, wbf + 1 * WSLOT);
  k_convw<<<4096, 256, 0, stream>>>(Wq_r, wbf + 2 * WSLOT);
  k_convw<<<4096, 256, 0, stream>>>(Wq_i, wbf + 3 * WSLOT);
  k_convw<<<4096, 256, 0, stream>>>(Wk_r, wbf + 4 * WSLOT);
  k_convw<<<4096, 256, 0, stream>>>(Wk_i, wbf + 5 * WSLOT);
  k_convw<<<4096, 256, 0, stream>>>(Wv_r, wbf + 6 * WSLOT);
  k_convw<<<4096, 256, 0, stream>>>(Wv_i, wbf + 7 * WSLOT);

  k_init<<<2048, 256, 0, stream>>>(xr, xi, sr, si, accb, memv, ptrv, rem0, crbf, cibf);

  dim3 ggrid(DD / 64, (BB * SS) / 64, MM);        // 256 blocks
  dim3 qgrid(DD / 64, BB, MM * 3);                // (8,4,12) = 384 blocks x 512 thr
  dim3 smgrid(1, SS / 32, BB * MM);               // 64 blocks
  dim3 pvgrid(DD / 64, SS / 64, BB * MM);         // 256 blocks

  for (int step = 0; step < NSTEPS; ++step) {
    float* rin = (step & 1) ? rem1 : rem0;
    float* rout = (step & 1) ? rem0 : rem1;
    k_flatctrl<<<BB, 256, 0, stream>>>(sr, si, ctrl_w, ctrl_b, ptrv, flat, nptrg, wmg,
                                       stacc, scorev, confv, haltacc);
    k_gemm_mfma<<<ggrid, 256, 0, stream>>>(crbf, cibf, wbf + 0 * WSLOT, wbf + 1 * WSLOT, zr, zi);
    k_lnphase<<<BB * MM * SS, 128, 0, stream>>>(zr, zi, ln_scale, ln_shift, mod_bias, zbr, zbi);
    k_gemm_qkv<<<qgrid, 512, 0, stream>>>(zbr, zbi, wbf, WSLOT, qbr, qbi, kbr, kbi, vbr, vbi);
    k_scores_sm<<<smgrid, 256, 0, stream>>>(qbr, qbi, kbr, kbi, Pb);
    k_pv<<<pvgrid, 256, 0, stream>>>(Pb, vbr, vbi, gate_mask, score_w, conf_w, halt_w,
                                     prb, pib, scorev, confv, haltacc);
    k_memup<<<BB * 4, 256, 0, stream>>>(flat, nptrg, wmg, memv, readv,
                                        st_score_w, st_conf_w, stacc,
                                        haltacc, halt_b, rin, rout, coeff);
    k_combine<<<BB * SS, 256, 0, stream>>>(prb, pib, scorev, confv, score_b, conf_b,
                                           stacc, st_score_b, st_conf_b, readv, coeff,
                                           xr, xi, sr, si, accb, crbf, cibf);
  }

  k_final<<<(BB * SS * 2 * DD) / 256, 256, 0, stream>>>(accb, rem0, sr, si, out);
}

// Round 10
// 2437.858 us; speedup vs baseline: 1.0473x; 1.0473x over previous
//
#include <hip/hip_runtime.h>

#define DD 512
#define MM 4
#define BB 4
#define SS 128
#define KK 32
#define NSTEPS 16
#define EPSF 1e-6f
#define SCALEF 0.04419417382415922f  // 512^-0.5

typedef unsigned short u16;
typedef __bf16 bf16x8 __attribute__((ext_vector_type(8)));
typedef u16 u16x8 __attribute__((ext_vector_type(8)));
typedef float f32x16 __attribute__((ext_vector_type(16)));

__device__ inline void split_bf16(float x, u16& h, u16& l) {
  __bf16 hb = (__bf16)x;
  float hf = (float)hb;
  __bf16 lb = (__bf16)(x - hf);
  h = __builtin_bit_cast(u16, hb);
  l = __builtin_bit_cast(u16, lb);
}

// ---------------- weight fp32 -> split bf16 [row][1024] (hi | lo) ----------------
__global__ void k_convw(const float* __restrict__ src, u16* __restrict__ dst) {
  int idx = blockIdx.x * 256 + threadIdx.x;
  int row = idx >> 9, k = idx & 511;
  u16 h, l;
  split_bf16(src[idx], h, l);
  dst[(size_t)row * 1024 + k] = h;
  dst[(size_t)row * 1024 + 512 + k] = l;
}

// ---------------- init ----------------
__global__ void k_init(const float* __restrict__ xr, const float* __restrict__ xi,
                       float* __restrict__ sr, float* __restrict__ si,
                       float* __restrict__ acc, float* __restrict__ memv,
                       float* __restrict__ ptrv, float* __restrict__ rem,
                       u16* __restrict__ crbf, u16* __restrict__ cibf) {
  int idx = blockIdx.x * 256 + threadIdx.x;
  if (idx < BB * SS * 2 * DD) acc[idx] = 0.f;
  if (idx < BB * SS * DD) {
    float a = xr[idx], b = xi[idx];
    sr[idx] = a; si[idx] = b;
    int row = idx >> 9, d = idx & 511;
    u16 h, l;
    split_bf16(a, h, l);
    crbf[(size_t)row * 1024 + d] = h;
    crbf[(size_t)row * 1024 + 512 + d] = l;
    split_bf16(b, h, l);
    cibf[(size_t)row * 1024 + d] = h;
    cibf[(size_t)row * 1024 + 512 + d] = l;
  }
  if (idx < BB * KK * 2 * DD) memv[idx] = 0.f;
  if (idx < BB * KK) ptrv[idx] = ((idx & (KK - 1)) == 0) ? 1.f : 0.f;
  if (idx < BB) rem[idx] = 1.f;
}

// ---------------- flat_in + control softmax + ptr update + zero logit accs ----------------
__global__ void k_flatctrl(const float* __restrict__ sr, const float* __restrict__ si,
                           const float* __restrict__ ctrl_w, const float* __restrict__ ctrl_b,
                           float* __restrict__ ptrv, float* __restrict__ flat_in,
                           float* __restrict__ nptrg, float* __restrict__ wmg,
                           float* __restrict__ stacc,
                           float* __restrict__ scorev, float* __restrict__ confv,
                           float* __restrict__ haltacc) {
  int b = blockIdx.x;
  int tid = threadIdx.x;  // 256
  __shared__ float red[3 * 256];
  __shared__ float ctrl[3], optr[KK], nptr_s[KK], wm_s[KK], normf;

  int zid = b * 256 + tid;
  scorev[zid] = 0.f; scorev[zid + 1024] = 0.f;
  confv[zid] = 0.f; confv[zid + 1024] = 0.f;
  haltacc[zid] = 0.f; haltacc[zid + 1024] = 0.f;

  if (tid < KK) optr[tid] = ptrv[b * KK + tid];

  int e4 = tid * 4;
  const float* basep = (e4 < DD) ? sr : si;
  int d4 = (e4 < DD) ? e4 : (e4 - DD);
  float4 accv = make_float4(0.f, 0.f, 0.f, 0.f);
  size_t base = (size_t)b * SS * DD + d4;
  for (int s = 0; s < SS; s++) {
    float4 v = *(const float4*)&basep[base + (size_t)s * DD];
    accv.x += v.x; accv.y += v.y; accv.z += v.z; accv.w += v.w;
  }
  accv.x *= (1.0f / SS); accv.y *= (1.0f / SS); accv.z *= (1.0f / SS); accv.w *= (1.0f / SS);
  *(float4*)&flat_in[b * 2 * DD + e4] = accv;
  float fv[4] = {accv.x, accv.y, accv.z, accv.w};
  float d0 = 0.f, d1 = 0.f, d2 = 0.f;
#pragma unroll
  for (int j = 0; j < 4; j++) {
    d0 += fv[j] * ctrl_w[(e4 + j) * 3 + 0];
    d1 += fv[j] * ctrl_w[(e4 + j) * 3 + 1];
    d2 += fv[j] * ctrl_w[(e4 + j) * 3 + 2];
  }
  red[tid] = d0; red[256 + tid] = d1; red[512 + tid] = d2;
  __syncthreads();
  for (int off = 128; off > 0; off >>= 1) {
    if (tid < off) {
      red[tid] += red[tid + off];
      red[256 + tid] += red[256 + tid + off];
      red[512 + tid] += red[512 + tid + off];
    }
    __syncthreads();
  }
  if (tid == 0) {
    float l0 = red[0] + ctrl_b[0], l1 = red[256] + ctrl_b[1], l2 = red[512] + ctrl_b[2];
    float mx = fmaxf(l0, fmaxf(l1, l2));
    float e0 = expf(l0 - mx), e1 = expf(l1 - mx), e2 = expf(l2 - mx);
    float s = e0 + e1 + e2;
    ctrl[0] = e0 / s; ctrl[1] = e1 / s; ctrl[2] = e2 / s;
    stacc[b * 2] = 0.f; stacc[b * 2 + 1] = 0.f;
  }
  __syncthreads();
  if (tid < KK) {
    float up = optr[(tid + KK - 1) & (KK - 1)];
    float dn = optr[(tid + 1) & (KK - 1)];
    float cu = optr[tid];
    nptr_s[tid] = ctrl[0] * up + ctrl[1] * dn + ctrl[2] * cu;
    wm_s[tid] = ctrl[0] * up;
  }
  __syncthreads();
  if (tid == 0) {
    float s = 0.f;
    for (int k = 0; k < KK; k++) s += nptr_s[k];
    normf = 1.f / (s + EPSF);
  }
  __syncthreads();
  if (tid < KK) {
    float np = nptr_s[tid] * normf;
    ptrv[b * KK + tid] = np;
    nptrg[b * KK + tid] = np;
    wmg[b * KK + tid] = wm_s[tid];
  }
}

#define LSTR 72   // LDS row stride for 64-wide tiles (144 B)
#define LST2 40   // LDS row stride for 32-wide hi/lo tiles (80 B, 16B-aligned)

// ---------------- Wl complex NT GEMM: BK=32 hi+lo staged, 3 segs from LDS ----------------
__global__ __launch_bounds__(256) void k_gemm_mfma(
    const u16* __restrict__ Ar, const u16* __restrict__ Ai,
    const u16* __restrict__ Wr, const u16* __restrict__ Wi,
    float* __restrict__ Cr, float* __restrict__ Ci) {
  __shared__ u16 sAr[2][64][LST2], sAi[2][64][LST2], sWr[2][64][LST2], sWi[2][64][LST2];
  int m = blockIdx.z;
  int row_blk = blockIdx.y * 64, o_blk = blockIdx.x * 64;
  int tid = threadIdx.x;

  int lrow = tid >> 2, lc8 = (tid & 3) << 3;   // 64 rows x 4 col-groups of 8
  size_t arow = (size_t)(row_blk + lrow);      // dense b*S+s rows
  size_t wrow = (size_t)m * DD + o_blk + lrow;

  int wave = tid >> 6, lane = tid & 63;
  int wr_ = (wave >> 1) * 32, wc_ = (wave & 1) * 32;
  int l31 = lane & 31, khalf = (lane >> 5) * 8;

  f32x16 accP, accN, accI;
  for (int i = 0; i < 16; i++) { accP[i] = 0.f; accN[i] = 0.f; accI[i] = 0.f; }

  // prologue: chunk 0 (hi and lo halves)
  u16x8 g0 = *(const u16x8*)&Ar[arow * 1024 + lc8];
  u16x8 g1 = *(const u16x8*)&Ar[arow * 1024 + 512 + lc8];
  u16x8 g2 = *(const u16x8*)&Ai[arow * 1024 + lc8];
  u16x8 g3 = *(const u16x8*)&Ai[arow * 1024 + 512 + lc8];
  u16x8 g4 = *(const u16x8*)&Wr[wrow * 1024 + lc8];
  u16x8 g5 = *(const u16x8*)&Wr[wrow * 1024 + 512 + lc8];
  u16x8 g6 = *(const u16x8*)&Wi[wrow * 1024 + lc8];
  u16x8 g7 = *(const u16x8*)&Wi[wrow * 1024 + 512 + lc8];

  for (int it = 0; it < 16; ++it) {
    __syncthreads();
    *(u16x8*)&sAr[0][lrow][lc8] = g0;
    *(u16x8*)&sAr[1][lrow][lc8] = g1;
    *(u16x8*)&sAi[0][lrow][lc8] = g2;
    *(u16x8*)&sAi[1][lrow][lc8] = g3;
    *(u16x8*)&sWr[0][lrow][lc8] = g4;
    *(u16x8*)&sWr[1][lrow][lc8] = g5;
    *(u16x8*)&sWi[0][lrow][lc8] = g6;
    *(u16x8*)&sWi[1][lrow][lc8] = g7;
    u16x8 n0, n1, n2, n3, n4, n5, n6, n7;
    if (it < 15) {
      int k0 = (it + 1) * 32;
      n0 = *(const u16x8*)&Ar[arow * 1024 + k0 + lc8];
      n1 = *(const u16x8*)&Ar[arow * 1024 + 512 + k0 + lc8];
      n2 = *(const u16x8*)&Ai[arow * 1024 + k0 + lc8];
      n3 = *(const u16x8*)&Ai[arow * 1024 + 512 + k0 + lc8];
      n4 = *(const u16x8*)&Wr[wrow * 1024 + k0 + lc8];
      n5 = *(const u16x8*)&Wr[wrow * 1024 + 512 + k0 + lc8];
      n6 = *(const u16x8*)&Wi[wrow * 1024 + k0 + lc8];
      n7 = *(const u16x8*)&Wi[wrow * 1024 + 512 + k0 + lc8];
    }
    __syncthreads();
    // 3 segments: (Ah,Wh), (Al,Wh), (Ah,Wl); 2 kk-steps each; 24 MFMA per barrier
#pragma unroll
    for (int seg = 0; seg < 3; seg++) {
      int ah = (seg == 1) ? 1 : 0;
      int wh = (seg == 2) ? 1 : 0;
#pragma unroll
      for (int kk = 0; kk < 32; kk += 16) {
        bf16x8 fAr = *(const bf16x8*)&sAr[ah][wr_ + l31][kk + khalf];
        bf16x8 fAi = *(const bf16x8*)&sAi[ah][wr_ + l31][kk + khalf];
        bf16x8 fWr = *(const bf16x8*)&sWr[wh][wc_ + l31][kk + khalf];
        bf16x8 fWi = *(const bf16x8*)&sWi[wh][wc_ + l31][kk + khalf];
        accP = __builtin_amdgcn_mfma_f32_32x32x16_bf16(fAr, fWr, accP, 0, 0, 0);
        accN = __builtin_amdgcn_mfma_f32_32x32x16_bf16(fAi, fWi, accN, 0, 0, 0);
        accI = __builtin_amdgcn_mfma_f32_32x32x16_bf16(fAi, fWr, accI, 0, 0, 0);
        accI = __builtin_amdgcn_mfma_f32_32x32x16_bf16(fAr, fWi, accI, 0, 0, 0);
      }
    }
    if (it < 15) {
      g0 = n0; g1 = n1; g2 = n2; g3 = n3; g4 = n4; g5 = n5; g6 = n6; g7 = n7;
    }
  }

  int o = o_blk + wc_ + l31;
#pragma unroll
  for (int reg = 0; reg < 16; reg++) {
    int r_in = (reg & 3) + 8 * (reg >> 2) + 4 * (lane >> 5);
    int gr = row_blk + wr_ + r_in;
    int b = gr >> 7, s = gr & (SS - 1);
    size_t crow = (size_t)((b * MM + m) * SS + s);
    Cr[crow * DD + o] = accP[reg] - accN[reg];
    Ci[crow * DD + o] = accI[reg];
  }
}

// ---------------- merged Q/K/V GEMM: BK=32 hi+lo staged, 3 segs from LDS ----------------
__global__ __launch_bounds__(256) void k_gemm_qkv(
    const u16* __restrict__ Ar, const u16* __restrict__ Ai,
    const u16* __restrict__ wbf, size_t WSLOT,
    u16* __restrict__ qbr, u16* __restrict__ qbi,
    u16* __restrict__ kbr, u16* __restrict__ kbi,
    u16* __restrict__ vbr, u16* __restrict__ vbi) {
  __shared__ u16 sAr[2][64][LST2], sAi[2][64][LST2], sWr[2][64][LST2], sWi[2][64][LST2];
  int zid = blockIdx.z;
  int m = zid / 3, w = zid - 3 * m;
  const u16* Wr = wbf + (size_t)(2 + 2 * w) * WSLOT;
  const u16* Wi = Wr + WSLOT;
  int row_blk = blockIdx.y * 64, o_blk = blockIdx.x * 64;
  int tid = threadIdx.x;

  int lrow = tid >> 2, lc8 = (tid & 3) << 3;
  int gr0 = row_blk + lrow;
  size_t arow = (size_t)(((gr0 >> 7) * MM + m) * SS + (gr0 & (SS - 1)));
  size_t wrow = (size_t)m * DD + o_blk + lrow;

  int wave = tid >> 6, lane = tid & 63;
  int wr_ = (wave >> 1) * 32, wc_ = (wave & 1) * 32;
  int l31 = lane & 31, khalf = (lane >> 5) * 8;

  f32x16 accP, accN, accI;
  for (int i = 0; i < 16; i++) { accP[i] = 0.f; accN[i] = 0.f; accI[i] = 0.f; }

  u16x8 g0 = *(const u16x8*)&Ar[arow * 1024 + lc8];
  u16x8 g1 = *(const u16x8*)&Ar[arow * 1024 + 512 + lc8];
  u16x8 g2 = *(const u16x8*)&Ai[arow * 1024 + lc8];
  u16x8 g3 = *(const u16x8*)&Ai[arow * 1024 + 512 + lc8];
  u16x8 g4 = *(const u16x8*)&Wr[wrow * 1024 + lc8];
  u16x8 g5 = *(const u16x8*)&Wr[wrow * 1024 + 512 + lc8];
  u16x8 g6 = *(const u16x8*)&Wi[wrow * 1024 + lc8];
  u16x8 g7 = *(const u16x8*)&Wi[wrow * 1024 + 512 + lc8];

  for (int it = 0; it < 16; ++it) {
    __syncthreads();
    *(u16x8*)&sAr[0][lrow][lc8] = g0;
    *(u16x8*)&sAr[1][lrow][lc8] = g1;
    *(u16x8*)&sAi[0][lrow][lc8] = g2;
    *(u16x8*)&sAi[1][lrow][lc8] = g3;
    *(u16x8*)&sWr[0][lrow][lc8] = g4;
    *(u16x8*)&sWr[1][lrow][lc8] = g5;
    *(u16x8*)&sWi[0][lrow][lc8] = g6;
    *(u16x8*)&sWi[1][lrow][lc8] = g7;
    u16x8 n0, n1, n2, n3, n4, n5, n6, n7;
    if (it < 15) {
      int k0 = (it + 1) * 32;
      n0 = *(const u16x8*)&Ar[arow * 1024 + k0 + lc8];
      n1 = *(const u16x8*)&Ar[arow * 1024 + 512 + k0 + lc8];
      n2 = *(const u16x8*)&Ai[arow * 1024 + k0 + lc8];
      n3 = *(const u16x8*)&Ai[arow * 1024 + 512 + k0 + lc8];
      n4 = *(const u16x8*)&Wr[wrow * 1024 + k0 + lc8];
      n5 = *(const u16x8*)&Wr[wrow * 1024 + 512 + k0 + lc8];
      n6 = *(const u16x8*)&Wi[wrow * 1024 + k0 + lc8];
      n7 = *(const u16x8*)&Wi[wrow * 1024 + 512 + k0 + lc8];
    }
    __syncthreads();
#pragma unroll
    for (int seg = 0; seg < 3; seg++) {
      int ah = (seg == 1) ? 1 : 0;
      int wh = (seg == 2) ? 1 : 0;
#pragma unroll
      for (int kk = 0; kk < 32; kk += 16) {
        bf16x8 fAr = *(const bf16x8*)&sAr[ah][wr_ + l31][kk + khalf];
        bf16x8 fAi = *(const bf16x8*)&sAi[ah][wr_ + l31][kk + khalf];
        bf16x8 fWr = *(const bf16x8*)&sWr[wh][wc_ + l31][kk + khalf];
        bf16x8 fWi = *(const bf16x8*)&sWi[wh][wc_ + l31][kk + khalf];
        accP = __builtin_amdgcn_mfma_f32_32x32x16_bf16(fAr, fWr, accP, 0, 0, 0);
        accN = __builtin_amdgcn_mfma_f32_32x32x16_bf16(fAi, fWi, accN, 0, 0, 0);
        accI = __builtin_amdgcn_mfma_f32_32x32x16_bf16(fAi, fWr, accI, 0, 0, 0);
        accI = __builtin_amdgcn_mfma_f32_32x32x16_bf16(fAr, fWi, accI, 0, 0, 0);
      }
    }
    if (it < 15) {
      g0 = n0; g1 = n1; g2 = n2; g3 = n3; g4 = n4; g5 = n5; g6 = n6; g7 = n7;
    }
  }

  u16* Cr = (w == 0) ? qbr : ((w == 1) ? kbr : vbr);
  u16* Ci = (w == 0) ? qbi : ((w == 1) ? kbi : vbi);
  int o = o_blk + wc_ + l31;
#pragma unroll
  for (int reg = 0; reg < 16; reg++) {
    int r_in = (reg & 3) + 8 * (reg >> 2) + 4 * (lane >> 5);
    int gr = row_blk + wr_ + r_in;
    int b = gr >> 7, s = gr & (SS - 1);
    size_t crow = (size_t)((b * MM + m) * SS + s);
    u16 h, l;
    split_bf16(accP[reg] - accN[reg], h, l);
    Cr[crow * 1024 + o] = h;
    Cr[crow * 1024 + 512 + o] = l;
    split_bf16(accI[reg], h, l);
    Ci[crow * 1024 + o] = h;
    Ci[crow * 1024 + 512 + o] = l;
  }
}

// ---------------- scores (32 rows x 128 cols per block) + fused softmax -> split P ----------------
__global__ __launch_bounds__(256) void k_scores_sm(
    const u16* __restrict__ Q_r, const u16* __restrict__ Q_i,
    const u16* __restrict__ K_r, const u16* __restrict__ K_i,
    u16* __restrict__ Pb) {
  __shared__ __align__(16) char smem[46080];
  u16 (*sQr)[LSTR] = (u16(*)[LSTR])smem;
  u16 (*sQi)[LSTR] = (u16(*)[LSTR])(smem + 4608);
  u16 (*sKr)[LSTR] = (u16(*)[LSTR])(smem + 9216);
  u16 (*sKi)[LSTR] = (u16(*)[LSTR])(smem + 27648);
  float (*stile)[132] = (float(*)[132])smem;

  int bm = blockIdx.z;
  int s_blk = blockIdx.y * 32;
  int tid = threadIdx.x;
  int lrow = tid >> 3, lk8 = (tid & 7) << 3;
  size_t qrow = (size_t)(bm * SS + s_blk + lrow);
  size_t krow = (size_t)(bm * SS + lrow);

  int wave = tid >> 6, lane = tid & 63;
  int tcol_w = wave * 32;
  int l31 = lane & 31, khalf = (lane >> 5) * 8;

  f32x16 acc;
  for (int i = 0; i < 16; i++) acc[i] = 0.f;

  for (int it = 0; it < 24; ++it) {
    int seg = it >> 3, k0 = (it & 7) * 64;
    int qofs = (seg == 1) ? 512 : 0;
    int kofs = (seg == 2) ? 512 : 0;
    u16x8 q0 = *(const u16x8*)&Q_r[qrow * 1024 + qofs + k0 + lk8];
    u16x8 q1 = *(const u16x8*)&Q_i[qrow * 1024 + qofs + k0 + lk8];
    u16x8 kr0 = *(const u16x8*)&K_r[(krow + 0) * 1024 + kofs + k0 + lk8];
    u16x8 kr1 = *(const u16x8*)&K_r[(krow + 32) * 1024 + kofs + k0 + lk8];
    u16x8 kr2 = *(const u16x8*)&K_r[(krow + 64) * 1024 + kofs + k0 + lk8];
    u16x8 kr3 = *(const u16x8*)&K_r[(krow + 96) * 1024 + kofs + k0 + lk8];
    u16x8 ki0 = *(const u16x8*)&K_i[(krow + 0) * 1024 + kofs + k0 + lk8];
    u16x8 ki1 = *(const u16x8*)&K_i[(krow + 32) * 1024 + kofs + k0 + lk8];
    u16x8 ki2 = *(const u16x8*)&K_i[(krow + 64) * 1024 + kofs + k0 + lk8];
    u16x8 ki3 = *(const u16x8*)&K_i[(krow + 96) * 1024 + kofs + k0 + lk8];
    __syncthreads();
    *(u16x8*)&sQr[lrow][lk8] = q0;
    *(u16x8*)&sQi[lrow][lk8] = q1;
    *(u16x8*)&sKr[lrow][lk8] = kr0;
    *(u16x8*)&sKr[lrow + 32][lk8] = kr1;
    *(u16x8*)&sKr[lrow + 64][lk8] = kr2;
    *(u16x8*)&sKr[lrow + 96][lk8] = kr3;
    *(u16x8*)&sKi[lrow][lk8] = ki0;
    *(u16x8*)&sKi[lrow + 32][lk8] = ki1;
    *(u16x8*)&sKi[lrow + 64][lk8] = ki2;
    *(u16x8*)&sKi[lrow + 96][lk8] = ki3;
    __syncthreads();
#pragma unroll
    for (int kk = 0; kk < 64; kk += 16) {
      bf16x8 fQr = *(const bf16x8*)&sQr[l31][kk + khalf];
      bf16x8 fQi = *(const bf16x8*)&sQi[l31][kk + khalf];
      bf16x8 fKr = *(const bf16x8*)&sKr[tcol_w + l31][kk + khalf];
      bf16x8 fKi = *(const bf16x8*)&sKi[tcol_w + l31][kk + khalf];
      acc = __builtin_amdgcn_mfma_f32_32x32x16_bf16(fQr, fKr, acc, 0, 0, 0);
      acc = __builtin_amdgcn_mfma_f32_32x32x16_bf16(fQi, fKi, acc, 0, 0, 0);
    }
  }

  __syncthreads();
#pragma unroll
  for (int reg = 0; reg < 16; reg++) {
    int r = (reg & 3) + 8 * (reg >> 2) + 4 * (lane >> 5);
    stile[r][tcol_w + l31] = acc[reg] * SCALEF;
  }
  __syncthreads();
  int row = tid >> 3;
  int oct = tid & 7;
  float mx = -3.4e38f;
#pragma unroll
  for (int j = 0; j < 16; j++) mx = fmaxf(mx, stile[row][oct * 16 + j]);
  mx = fmaxf(mx, __shfl_xor(mx, 1));
  mx = fmaxf(mx, __shfl_xor(mx, 2));
  mx = fmaxf(mx, __shfl_xor(mx, 4));
  float ev[16];
  float sum = 0.f;
#pragma unroll
  for (int j = 0; j < 16; j++) {
    ev[j] = expf(stile[row][oct * 16 + j] - mx);
    sum += ev[j];
  }
  sum += __shfl_xor(sum, 1);
  sum += __shfl_xor(sum, 2);
  sum += __shfl_xor(sum, 4);
  float inv = 1.f / sum;
  size_t prow = (size_t)(bm * SS + s_blk + row) * 256;
#pragma unroll
  for (int j = 0; j < 16; j++) {
    int c = oct * 16 + j;
    u16 h, l;
    split_bf16(ev[j] * inv, h, l);
    Pb[prow + c] = h;
    Pb[prow + 128 + c] = l;
  }
}

// ---------------- P x V MFMA + gate -> pr/pi, fused score/conf/halt logit partials ----------------
__global__ __launch_bounds__(256) void k_pv(
    const u16* __restrict__ Pb, const u16* __restrict__ vbr, const u16* __restrict__ vbi,
    const float* __restrict__ gate_mask,
    const float* __restrict__ score_w, const float* __restrict__ conf_w,
    const float* __restrict__ halt_w,
    float* __restrict__ pr, float* __restrict__ pi,
    float* __restrict__ scorev, float* __restrict__ confv, float* __restrict__ haltacc) {
  __shared__ u16 sP[64][LSTR], sVr[64][LSTR], sVi[64][LSTR];
  __shared__ float rowAcc[64][3];
  int bm = blockIdx.z;
  int m = bm & (MM - 1);
  int s_blk = blockIdx.y * 64;
  int o_blk = blockIdx.x * 64;
  int tid = threadIdx.x;
  int lrow = tid >> 3, lk8 = (tid & 7) << 3;
  size_t prow0 = (size_t)(bm * SS + s_blk + lrow), prow1 = prow0 + 32;

  int wave = tid >> 6, lane = tid & 63;
  int wrow = (wave >> 1) * 32;
  int wcol = (wave & 1) * 32;
  int l31 = lane & 31, khalf = (lane >> 5) * 8;

  if (tid < 64) { rowAcc[tid][0] = 0.f; rowAcc[tid][1] = 0.f; rowAcc[tid][2] = 0.f; }

  f32x16 accR, accI;
  for (int i = 0; i < 16; i++) { accR[i] = 0.f; accI[i] = 0.f; }

  for (int it = 0; it < 6; ++it) {
    int seg = it >> 1, k0 = (it & 1) * 64;
    int pofs = (seg == 1) ? 128 : 0;
    int vofs = (seg == 2) ? 512 : 0;
    u16x8 p0 = *(const u16x8*)&Pb[prow0 * 256 + pofs + k0 + lk8];
    u16x8 p1 = *(const u16x8*)&Pb[prow1 * 256 + pofs + k0 + lk8];
    size_t vrow0 = (size_t)(bm * SS + k0 + lrow), vrow1 = vrow0 + 32;
    u16x8 v0 = *(const u16x8*)&vbr[vrow0 * 1024 + vofs + o_blk + lk8];
    u16x8 v1 = *(const u16x8*)&vbr[vrow1 * 1024 + vofs + o_blk + lk8];
    u16x8 w0 = *(const u16x8*)&vbi[vrow0 * 1024 + vofs + o_blk + lk8];
    u16x8 w1 = *(const u16x8*)&vbi[vrow1 * 1024 + vofs + o_blk + lk8];
    __syncthreads();
    *(u16x8*)&sP[lrow][lk8] = p0;
    *(u16x8*)&sP[lrow + 32][lk8] = p1;
    *(u16x8*)&sVr[lrow][lk8] = v0;
    *(u16x8*)&sVr[lrow + 32][lk8] = v1;
    *(u16x8*)&sVi[lrow][lk8] = w0;
    *(u16x8*)&sVi[lrow + 32][lk8] = w1;
    __syncthreads();
#pragma unroll
    for (int kk = 0; kk < 64; kk += 16) {
      bf16x8 fP = *(const bf16x8*)&sP[wrow + l31][kk + khalf];
      u16x8 ar, ai;
#pragma unroll
      for (int j = 0; j < 8; j++) {
        ar[j] = sVr[kk + khalf + j][wcol + l31];
        ai[j] = sVi[kk + khalf + j][wcol + l31];
      }
      accR = __builtin_amdgcn_mfma_f32_32x32x16_bf16(fP, __builtin_bit_cast(bf16x8, ar), accR, 0, 0, 0);
      accI = __builtin_amdgcn_mfma_f32_32x32x16_bf16(fP, __builtin_bit_cast(bf16x8, ai), accI, 0, 0, 0);
    }
  }

  int d = o_blk + wcol + l31;
  float g = 1.f / (1.f + expf(-gate_mask[m * DD + d]));
  float sw_r = score_w[m * 1024 + d], sw_i = score_w[m * 1024 + 512 + d];
  float cw_r = conf_w[m * 1024 + d],  cw_i = conf_w[m * 1024 + 512 + d];
  float hw_r = halt_w[m * 1024 + d],  hw_i = halt_w[m * 1024 + 512 + d];
#pragma unroll
  for (int reg = 0; reg < 16; reg++) {
    int r_in = (reg & 3) + 8 * (reg >> 2) + 4 * (lane >> 5);
    size_t crow = (size_t)(bm * SS + s_blk + wrow + r_in);
    float pR = accR[reg] * g, pI = accI[reg] * g;
    pr[crow * DD + d] = pR;
    pi[crow * DD + d] = pI;
    float sp = pR * sw_r + pI * sw_i;
    float cp = pR * cw_r + pI * cw_i;
    float hp = pR * hw_r + pI * hw_i;
#pragma unroll
    for (int msk = 16; msk >= 1; msk >>= 1) {
      sp += __shfl_xor(sp, msk);
      cp += __shfl_xor(cp, msk);
      hp += __shfl_xor(hp, msk);
    }
    if (l31 == 0) {
      int r = wrow + r_in;
      atomicAdd(&rowAcc[r][0], sp);
      atomicAdd(&rowAcc[r][1], cp);
      atomicAdd(&rowAcc[r][2], hp);
    }
  }
  __syncthreads();
  if (tid < 64) {
    size_t rowg = (size_t)(bm * SS + s_blk + tid);
    atomicAdd(&scorev[rowg], rowAcc[tid][0]);
    atomicAdd(&confv[rowg], rowAcc[tid][1]);
    atomicAdd(&haltacc[rowg], rowAcc[tid][2]);
  }
}

// ---------------- magnitude LN + phase renorm + mod scale -> split bf16 ----------------
__global__ void k_lnphase(const float* __restrict__ zr, const float* __restrict__ zi,
                          const float* __restrict__ ln_scale, const float* __restrict__ ln_shift,
                          const float* __restrict__ mod_bias,
                          u16* __restrict__ zbr, u16* __restrict__ zbi) {
  int row = blockIdx.x;
  int m = (row >> 7) & (MM - 1);
  int tid = threadIdx.x;  // 128
  size_t base = (size_t)row * DD;
  float zrv[4], ziv[4], rv[4];
  float sum = 0.f, sumsq = 0.f;
#pragma unroll
  for (int i = 0; i < 4; i++) {
    int o = tid + i * 128;
    float a = zr[base + o], bv = zi[base + o];
    zrv[i] = a; ziv[i] = bv;
    float r = sqrtf(a * a + bv * bv);
    rv[i] = r;
    float mg = r + EPSF;
    sum += mg;
    sumsq += mg * mg;
  }
  __shared__ float rs[128], rq[128];
  rs[tid] = sum; rq[tid] = sumsq;
  __syncthreads();
  for (int off = 64; off > 0; off >>= 1) {
    if (tid < off) { rs[tid] += rs[tid + off]; rq[tid] += rq[tid + off]; }
    __syncthreads();
  }
  float mean = rs[0] * (1.0f / DD);
  float var = (rq[0] - (float)DD * mean * mean) * (1.0f / (DD - 1));
  float inv = 1.0f / sqrtf(var + EPSF);
#pragma unroll
  for (int i = 0; i < 4; i++) {
    int o = tid + i * 128;
    float mg = rv[i] + EPSF;
    float nm = (mg - mean) * inv * ln_scale[m * DD + o] + ln_shift[m * DD + o];
    float r = rv[i];
    float cosp, sinp;
    if (r > 0.f) { cosp = zrv[i] / r; sinp = ziv[i] / r; }
    else { cosp = 1.f; sinp = 0.f; }
    float z1r = nm * cosp, z1i = nm * sinp;
    float nrm = sqrtf(z1r * z1r + z1i * z1i) + EPSF;
    float sc = fmaxf(nrm + mod_bias[m * DD + o], 0.f) / nrm;
    u16 h, l;
    split_bf16(z1r * sc, h, l);
    zbr[(size_t)row * 1024 + o] = h;
    zbr[(size_t)row * 1024 + 512 + o] = l;
    split_bf16(z1i * sc, h, l);
    zbi[(size_t)row * 1024 + o] = h;
    zbi[(size_t)row * 1024 + 512 + o] = l;
  }
}

// ---------------- stack mem update + read + st dots; chunk0 also does halt p + coeff/rem ----------------
__global__ void k_memup(const float* __restrict__ flat_in,
                        const float* __restrict__ nptrg, const float* __restrict__ wmg,
                        float* __restrict__ memv, float* __restrict__ readv,
                        const float* __restrict__ st_score_w, const float* __restrict__ st_conf_w,
                        float* __restrict__ stacc,
                        const float* __restrict__ haltacc, const float* __restrict__ halt_b,
                        const float* __restrict__ rem_in, float* __restrict__ rem_out,
                        float* __restrict__ coeff) {
  int b = blockIdx.x >> 2;
  int chunk = blockIdx.x & 3;
  int tid = threadIdx.x;           // 256
  int e = chunk * 256 + tid;
  __shared__ float nptr[KK], wm[KK];
  __shared__ float red[256], red2[256], red3[256];
  if (tid < KK) { nptr[tid] = nptrg[b * KK + tid]; wm[tid] = wmg[b * KK + tid]; }

  float hsum = 0.f;
  if (chunk == 0) {
    float h0 = haltacc[b * 512 + tid] + halt_b[tid >> 7];
    float h1 = haltacc[b * 512 + 256 + tid] + halt_b[(256 + tid) >> 7];
    hsum = 1.f / (1.f + expf(-h0)) + 1.f / (1.f + expf(-h1));
  }
  __syncthreads();
  float fl = flat_in[b * 2 * DD + e];
  float racc = 0.f;
#pragma unroll
  for (int k = 0; k < KK; k++) {
    size_t idx = ((size_t)(b * KK + k)) * 2 * DD + e;
    float nm = wm[k] * fl + memv[idx] * (1.f - wm[k]);
    memv[idx] = nm;
    racc += nm * nptr[k];
  }
  readv[b * 2 * DD + e] = racc;
  red[tid] = racc * st_score_w[e];
  red2[tid] = racc * st_conf_w[e];
  red3[tid] = hsum;
  __syncthreads();
  for (int off = 128; off > 0; off >>= 1) {
    if (tid < off) { red[tid] += red[tid + off]; red2[tid] += red2[tid + off]; red3[tid] += red3[tid + off]; }
    __syncthreads();
  }
  if (tid == 0) {
    atomicAdd(&stacc[b * 2], red[0]);
    atomicAdd(&stacc[b * 2 + 1], red2[0]);
    if (chunk == 0) {
      float p = red3[0] * (1.0f / (MM * SS));
      float r = rem_in[b];
      coeff[b] = p * r;
      rem_out[b] = r * (1.f - p);
    }
  }
}

// ---------------- module-mix softmax + stv + new state + acc + next-step c ----------------
__global__ void k_combine(const float* __restrict__ pr, const float* __restrict__ pi,
                          const float* __restrict__ scorev, const float* __restrict__ confv,
                          const float* __restrict__ score_b, const float* __restrict__ conf_b,
                          const float* __restrict__ stacc,
                          const float* __restrict__ st_score_b, const float* __restrict__ st_conf_b,
                          const float* __restrict__ readv, const float* __restrict__ coeff,
                          const float* __restrict__ xr, const float* __restrict__ xi,
                          float* __restrict__ sr, float* __restrict__ si, float* __restrict__ acc,
                          u16* __restrict__ crbf, u16* __restrict__ cibf) {
  int bs = blockIdx.x;
  int b = bs >> 7, s = bs & (SS - 1);
  int tid = threadIdx.x;  // 256
  __shared__ float w[5];
  if (tid == 0) {
    float l[5];
    for (int m = 0; m < MM; m++) {
      int r = (b * MM + m) * SS + s;
      float sc = scorev[r] + score_b[m];
      float cf2 = 1.f / (1.f + expf(-(confv[r] + conf_b[m])));
      l[m] = sc * cf2;
    }
    float sv = stacc[b * 2] + st_score_b[0];
    float cv = 1.f / (1.f + expf(-(stacc[b * 2 + 1] + st_conf_b[0])));
    l[4] = sv * cv;
    float mx = l[0];
    for (int j = 1; j < 5; j++) mx = fmaxf(mx, l[j]);
    float sum = 0.f;
    for (int j = 0; j < 5; j++) { l[j] = expf(l[j] - mx); sum += l[j]; }
    for (int j = 0; j < 5; j++) w[j] = l[j] / sum;
  }
  __syncthreads();
  float cf = coeff[b];
#pragma unroll
  for (int i = 0; i < 2; i++) {
    int d = tid + i * 256;
    float nsr = w[4] * readv[b * 2 * DD + d];
    float nsi = w[4] * readv[b * 2 * DD + DD + d];
#pragma unroll
    for (int m = 0; m < MM; m++) {
      size_t off = ((size_t)((b * MM + m) * SS + s)) * DD + d;
      nsr += w[m] * pr[off];
      nsi += w[m] * pi[off];
    }
    size_t sidx = (size_t)bs * DD + d;
    sr[sidx] = nsr;
    si[sidx] = nsi;
    size_t aoff = (size_t)bs * 2 * DD;
    acc[aoff + d] += cf * nsr;
    acc[aoff + DD + d] += cf * nsi;
    u16 h, l;
    split_bf16(0.5f * xr[sidx] + 0.5f * nsr, h, l);
    crbf[(size_t)bs * 1024 + d] = h;
    crbf[(size_t)bs * 1024 + 512 + d] = l;
    split_bf16(0.5f * xi[sidx] + 0.5f * nsi, h, l);
    cibf[(size_t)bs * 1024 + d] = h;
    cibf[(size_t)bs * 1024 + 512 + d] = l;
  }
}

// ---------------- out = acc + rem * concat(sr, si) ----------------
__global__ void k_final(const float* __restrict__ acc, const float* __restrict__ rem,
                        const float* __restrict__ sr, const float* __restrict__ si,
                        float* __restrict__ out) {
  int idx = blockIdx.x * 256 + threadIdx.x;
  int e = idx & (2 * DD - 1);
  int bs = idx >> 10;
  int b = bs >> 7;
  float v = (e < DD) ? sr[(size_t)bs * DD + e] : si[(size_t)bs * DD + e - DD];
  out[idx] = acc[idx] + rem[b] * v;
}

extern "C" void kernel_launch(void* const* d_in, const int* in_sizes, int n_in,
                              void* d_out, int out_size, void* d_ws, size_t ws_size,
                              hipStream_t stream) {
  const float* xr = (const float*)d_in[0];
  const float* xi = (const float*)d_in[1];
  const float* Wl_r = (const float*)d_in[2];
  const float* Wl_i = (const float*)d_in[3];
  const float* Wq_r = (const float*)d_in[4];
  const float* Wq_i = (const float*)d_in[5];
  const float* Wk_r = (const float*)d_in[6];
  const float* Wk_i = (const float*)d_in[7];
  const float* Wv_r = (const float*)d_in[8];
  const float* Wv_i = (const float*)d_in[9];
  const float* ln_scale = (const float*)d_in[10];
  const float* ln_shift = (const float*)d_in[11];
  const float* mod_bias = (const float*)d_in[12];
  const float* gate_mask = (const float*)d_in[13];
  const float* score_w = (const float*)d_in[14];
  const float* score_b = (const float*)d_in[15];
  const float* conf_w = (const float*)d_in[16];
  const float* conf_b = (const float*)d_in[17];
  const float* halt_w = (const float*)d_in[18];
  const float* halt_b = (const float*)d_in[19];
  const float* ctrl_w = (const float*)d_in[20];
  const float* ctrl_b = (const float*)d_in[21];
  const float* st_score_w = (const float*)d_in[22];
  const float* st_score_b = (const float*)d_in[23];
  const float* st_conf_w = (const float*)d_in[24];
  const float* st_conf_b = (const float*)d_in[25];
  float* out = (float*)d_out;

  const int BSD = BB * SS * DD;
  const int BMSD = BB * MM * SS * DD;
  const size_t WSLOT = (size_t)MM * DD * 1024;

  char* pc = (char*)d_ws;
  float* sr = (float*)pc; pc += (size_t)BSD * 4;
  float* si = (float*)pc; pc += (size_t)BSD * 4;
  float* zr = (float*)pc; pc += (size_t)BMSD * 4;
  float* zi = (float*)pc; pc += (size_t)BMSD * 4;
  float* prb = (float*)pc; pc += (size_t)BMSD * 4;
  float* pib = (float*)pc; pc += (size_t)BMSD * 4;
  float* scorev = (float*)pc; pc += (size_t)BB * MM * SS * 4;
  float* confv = (float*)pc; pc += (size_t)BB * MM * SS * 4;
  float* haltacc = (float*)pc; pc += (size_t)BB * MM * SS * 4;
  float* flat = (float*)pc; pc += (size_t)BB * 2 * DD * 4;
  float* stacc = (float*)pc; pc += 64;
  float* nptrg = (float*)pc; pc += (size_t)BB * KK * 4;
  float* wmg = (float*)pc; pc += (size_t)BB * KK * 4;
  float* memv = (float*)pc; pc += (size_t)BB * KK * 2 * DD * 4;
  float* ptrv = (float*)pc; pc += (size_t)BB * KK * 4;
  float* readv = (float*)pc; pc += (size_t)BB * 2 * DD * 4;
  float* accb = (float*)pc; pc += (size_t)BB * SS * 2 * DD * 4;
  float* rem0 = (float*)pc; pc += (size_t)BB * 4;
  float* rem1 = (float*)pc; pc += (size_t)BB * 4;
  float* coeff = (float*)pc; pc += (size_t)BB * 4;
  u16* crbf = (u16*)pc; pc += (size_t)BB * SS * 1024 * 2;
  u16* cibf = (u16*)pc; pc += (size_t)BB * SS * 1024 * 2;
  u16* zbr = (u16*)pc; pc += (size_t)BB * MM * SS * 1024 * 2;
  u16* zbi = (u16*)pc; pc += (size_t)BB * MM * SS * 1024 * 2;
  u16* qbr = (u16*)pc; pc += (size_t)BB * MM * SS * 1024 * 2;
  u16* qbi = (u16*)pc; pc += (size_t)BB * MM * SS * 1024 * 2;
  u16* kbr = (u16*)pc; pc += (size_t)BB * MM * SS * 1024 * 2;
  u16* kbi = (u16*)pc; pc += (size_t)BB * MM * SS * 1024 * 2;
  u16* vbr = (u16*)pc; pc += (size_t)BB * MM * SS * 1024 * 2;
  u16* vbi = (u16*)pc; pc += (size_t)BB * MM * SS * 1024 * 2;
  u16* Pb  = (u16*)pc; pc += (size_t)BB * MM * SS * 256 * 2;
  u16* wbf = (u16*)pc; pc += 8 * WSLOT * 2;

  k_convw<<<4096, 256, 0, stream>>>(Wl_r, wbf + 0 * WSLOT);
  k_convw<<<4096, 256, 0, stream>>>(Wl_i, wbf + 1 * WSLOT);
  k_convw<<<4096, 256, 0, stream>>>(Wq_r, wbf + 2 * WSLOT);
  k_convw<<<4096, 256, 0, stream>>>(Wq_i, wbf + 3 * WSLOT);
  k_convw<<<4096, 256, 0, stream>>>(Wk_r, wbf + 4 * WSLOT);
  k_convw<<<4096, 256, 0, stream>>>(Wk_i, wbf + 5 * WSLOT);
  k_convw<<<4096, 256, 0, stream>>>(Wv_r, wbf + 6 * WSLOT);
  k_convw<<<4096, 256, 0, stream>>>(Wv_i, wbf + 7 * WSLOT);

  k_init<<<2048, 256, 0, stream>>>(xr, xi, sr, si, accb, memv, ptrv, rem0, crbf, cibf);

  dim3 ggrid(DD / 64, (BB * SS) / 64, MM);        // 256 blocks
  dim3 qgrid(DD / 64, (BB * SS) / 64, MM * 3);    // (8,8,12) = 768 blocks x 256 thr
  dim3 smgrid(1, SS / 32, BB * MM);               // 64 blocks
  dim3 pvgrid(DD / 64, SS / 64, BB * MM);         // 256 blocks

  for (int step = 0; step < NSTEPS; ++step) {
    float* rin = (step & 1) ? rem1 : rem0;
    float* rout = (step & 1) ? rem0 : rem1;
    k_flatctrl<<<BB, 256, 0, stream>>>(sr, si, ctrl_w, ctrl_b, ptrv, flat, nptrg, wmg,
                                       stacc, scorev, confv, haltacc);
    k_gemm_mfma<<<ggrid, 256, 0, stream>>>(crbf, cibf, wbf + 0 * WSLOT, wbf + 1 * WSLOT, zr, zi);
    k_lnphase<<<BB * MM * SS, 128, 0, stream>>>(zr, zi, ln_scale, ln_shift, mod_bias, zbr, zbi);
    k_gemm_qkv<<<qgrid, 256, 0, stream>>>(zbr, zbi, wbf, WSLOT, qbr, qbi, kbr, kbi, vbr, vbi);
    k_scores_sm<<<smgrid, 256, 0, stream>>>(qbr, qbi, kbr, kbi, Pb);
    k_pv<<<pvgrid, 256, 0, stream>>>(Pb, vbr, vbi, gate_mask, score_w, conf_w, halt_w,
                                     prb, pib, scorev, confv, haltacc);
    k_memup<<<BB * 4, 256, 0, stream>>>(flat, nptrg, wmg, memv, readv,
                                        st_score_w, st_conf_w, stacc,
                                        haltacc, halt_b, rin, rout, coeff);
    k_combine<<<BB * SS, 256, 0, stream>>>(prb, pib, scorev, confv, score_b, conf_b,
                                           stacc, st_score_b, st_conf_b, readv, coeff,
                                           xr, xi, sr, si, accb, crbf, cibf);
  }

  k_final<<<(BB * SS * 2 * DD) / 256, 256, 0, stream>>>(accb, rem0, sr, si, out);
}